// Round 15
// baseline (136.323 us; speedup 1.0000x reference)
//
#include <hip/hip_runtime.h>
#include <stdint.h>

#define E_DIM   1024
#define HNUM    16
#define DH      64
#define BATCH   2
#define SEQ     2048
#define M_TOT   (BATCH*SEQ)   // 4096
#define LOG2E   1.44269504088896340736f

typedef __bf16 bf16x8 __attribute__((ext_vector_type(8)));
typedef __bf16 bf16x4 __attribute__((ext_vector_type(4)));
typedef float  f32x4  __attribute__((ext_vector_type(4)));
typedef float  f32x16 __attribute__((ext_vector_type(16)));
typedef unsigned short u16;
typedef unsigned int   u32;
typedef unsigned long long u64;
typedef u16 u16x8 __attribute__((ext_vector_type(8)));
typedef u32 u32x2 __attribute__((ext_vector_type(2)));
typedef u32 u32x4 __attribute__((ext_vector_type(4)));

__device__ __forceinline__ u16 f2bf(float f) {
    u32 u = __builtin_bit_cast(u32, f);
    u32 r = 0x7FFFu + ((u >> 16) & 1u);
    return (u16)((u + r) >> 16);
}

__device__ __forceinline__ void gload_lds16(const u16* g, u16* l) {
    __builtin_amdgcn_global_load_lds(
        (const __attribute__((address_space(1))) u32*)g,
        (__attribute__((address_space(3))) u32*)l, 16, 0, 0);
}

__device__ __forceinline__ u32 cvt_pk_bf16(float lo, float hi) {
    u32 r;
    asm("v_cvt_pk_bf16_f32 %0, %1, %2" : "=v"(r) : "v"(lo), "v"(hi));
    return r;
}

#define MFMA16(a,b,c) __builtin_amdgcn_mfma_f32_16x16x32_bf16((a),(b),(c),0,0,0)
#define MFMA32(a,b,c) __builtin_amdgcn_mfma_f32_32x32x16_bf16((a),(b),(c),0,0,0)

// ---------------- cast x (fp32 -> bf16) ----------------
__global__ __launch_bounds__(256) void cast_x_kernel(const float* __restrict__ x,
                                                     u16* __restrict__ out, int n) {
    int idx = (blockIdx.x * 256 + threadIdx.x) * 4;
    if (idx < n) {
        float4 v = *reinterpret_cast<const float4*>(x + idx);
        ushort4 o;
        o.x = f2bf(v.x); o.y = f2bf(v.y); o.z = f2bf(v.z); o.w = f2bf(v.w);
        *reinterpret_cast<ushort4*>(out + idx) = o;
    }
}

// ---------------- mask -> 64-bit bitmaps ----------------
__global__ __launch_bounds__(256) void maskbits_kernel(const int* __restrict__ mask,
                                                       u64* __restrict__ bits) {
    int i = blockIdx.x * 256 + threadIdx.x;
    u64 bl = __ballot(mask[i] != 0);
    if ((i & 63) == 0) bits[i >> 6] = bl;
}

// ---------------- weight transpose + cast: Wt[n][k] = bf16(W[k][n]) ----------------
__global__ void wtrans_kernel(const float* __restrict__ w0, const float* __restrict__ w1,
                              const float* __restrict__ w2, const float* __restrict__ w3,
                              u16* __restrict__ out) {
    __shared__ float tile[32][33];
    const float* w = blockIdx.z == 0 ? w0 : blockIdx.z == 1 ? w1 : blockIdx.z == 2 ? w2 : w3;
    const int n0 = blockIdx.x * 32, k0 = blockIdx.y * 32;
    #pragma unroll
    for (int j = 0; j < 4; j++) {
        int k = k0 + threadIdx.y + j * 8;
        tile[threadIdx.y + j * 8][threadIdx.x] = w[(size_t)k * E_DIM + n0 + threadIdx.x];
    }
    __syncthreads();
    u16* o = out + (size_t)blockIdx.z * E_DIM * E_DIM;
    #pragma unroll
    for (int j = 0; j < 4; j++) {
        int n = n0 + threadIdx.y + j * 8;
        o[(size_t)n * E_DIM + k0 + threadIdx.x] = f2bf(tile[threadIdx.x][threadIdx.y + j * 8]);
    }
}

// ---------------- GEMM (128x128, m97 structure) — used for out-proj ----------------
template <typename OutT>
__global__ __launch_bounds__(256) void gemm_kernel(
    const u16* __restrict__ A, const u16* __restrict__ Bt_base, OutT* __restrict__ C_base,
    const float* __restrict__ bias0, const float* __restrict__ bias1,
    const float* __restrict__ bias2, float scale0, int Mdim) {
    const int z = blockIdx.z;
    const u16* Bt = Bt_base + (size_t)z * E_DIM * E_DIM;
    OutT* C = C_base + (size_t)z * Mdim * E_DIM;
    const float* bias = (z == 0) ? bias0 : (z == 1 ? bias1 : bias2);
    const float scale = (z == 0) ? scale0 : 1.0f;

    __shared__ __align__(16) u16 Als[128 * 32];
    __shared__ __align__(16) u16 Bls[128 * 32];

    const int tid = threadIdx.x;
    const int lane = tid & 63;
    const int w = tid >> 6;
    const int wr = (w >> 1) * 64, wc = (w & 1) * 64;
    const int tm = blockIdx.y * 128, tn = blockIdx.x * 128;
    const int r4 = tid >> 2;
    const int c8 = (tid & 3) * 8;

    f32x4 acc[4][4] = {};

    for (int k0 = 0; k0 < E_DIM; k0 += 32) {
        gload_lds16(A + (size_t)(tm + r4) * E_DIM + k0 + c8, Als + tid * 8);
        gload_lds16(A + (size_t)(tm + 64 + r4) * E_DIM + k0 + c8, Als + 2048 + tid * 8);
        gload_lds16(Bt + (size_t)(tn + r4) * E_DIM + k0 + c8, Bls + tid * 8);
        gload_lds16(Bt + (size_t)(tn + 64 + r4) * E_DIM + k0 + c8, Bls + 2048 + tid * 8);
        __syncthreads();
        const int lr = lane & 15, lg = lane >> 4;
        bf16x8 af[4], bfr[4];
        #pragma unroll
        for (int m = 0; m < 4; m++)
            af[m] = *reinterpret_cast<const bf16x8*>(Als + (wr + m * 16 + lr) * 32 + lg * 8);
        #pragma unroll
        for (int n = 0; n < 4; n++)
            bfr[n] = *reinterpret_cast<const bf16x8*>(Bls + (wc + n * 16 + lr) * 32 + lg * 8);
        #pragma unroll
        for (int m = 0; m < 4; m++)
            #pragma unroll
            for (int n = 0; n < 4; n++)
                acc[m][n] = MFMA16(af[m], bfr[n], acc[m][n]);
        __syncthreads();
    }

    const int lr = lane & 15, lg = lane >> 4;
    #pragma unroll
    for (int m = 0; m < 4; m++) {
        #pragma unroll
        for (int n = 0; n < 4; n++) {
            const int col = tn + wc + n * 16 + lr;
            const float bv = bias[col];
            #pragma unroll
            for (int r = 0; r < 4; r++) {
                const int row = tm + wr + m * 16 + lg * 4 + r;
                float v = (acc[m][n][r] + bv) * scale;
                if constexpr (sizeof(OutT) == 2) {
                    C[(size_t)row * E_DIM + col] = f2bf(v);
                } else {
                    C[(size_t)row * E_DIM + col] = v;
                }
            }
        }
    }
}

// ---------------- gemm256: 256x128 tile, 8 waves, 3-slot ring, counted vmcnt ----------------
// C[4096][3072] = A[4096][1024] @ Bt[3072][1024]^T  (Bt = q,k,v weight slices contiguous).
// 512 thr, wave w owns rows [tm + w*32, +32). Swapped-operand MFMA32 (A-op = Bt rows with
// attn-verified krow remap; B-op = A rows; D: col=m=lane&31, n=(r&7)+8*hi+16*(r>>3)).
// LDS: 3-slot ring (A[256][32]+B[128][32] = 24KB/slot), staged 2 ahead via gload_lds,
// per-step s_waitcnt vmcnt(3) retires stage(k+1) BEFORE the barrier preceding its read
// (cross-wave safe, R13 discipline). XOR swizzle byte^=((byte>>7)&7)<<4 (involution:
// s() reads bits 7-9, flips 4-6) on LDS reads + pre-swizzled gload source. No ds_writes
// -> no lgkm at barriers. Bias + scale (z=0: Q pre-scale) fused in epilogue.
__global__ __launch_bounds__(512, 4) void gemm256_kernel(
    const u16* __restrict__ A, const u16* __restrict__ Bt, u16* __restrict__ Cb,
    const float* __restrict__ bias0, const float* __restrict__ bias1,
    const float* __restrict__ bias2, float scale0) {
    __shared__ __align__(16) u16 Als[3][256 * 32];   // 16KB/slot
    __shared__ __align__(16) u16 Bls[3][128 * 32];   // 8KB/slot

    const int tid = threadIdx.x;          // 0..511
    const int lane = tid & 63;
    const int w = tid >> 6;
    const int hi = lane >> 5;
    const int l31 = lane & 31;
    const int tm = blockIdx.x * 256;
    const int tn = blockIdx.y * 128;

    // A-op row remap (attn-verified bit 2<->3 swap)
    const int krow = (l31 & 3) | ((l31 & 4) << 1) | ((l31 & 8) >> 1) | (l31 & 16);

    // LDS read offsets (bytes, loop-invariant), swizzle byte^=((byte>>7)&7)<<4
    u32 aoff[2];
    #pragma unroll
    for (int ks = 0; ks < 2; ks++) {
        const u32 a = (u32)(w * 32 + l31) * 64 + ks * 32 + hi * 16;
        aoff[ks] = a ^ (((a >> 7) & 7) << 4);
    }
    u32 boff[4][2];
    #pragma unroll
    for (int nt = 0; nt < 4; nt++)
        #pragma unroll
        for (int ks = 0; ks < 2; ks++) {
            const u32 a = (u32)(nt * 32 + krow) * 64 + ks * 32 + hi * 16;
            boff[nt][ks] = a ^ (((a >> 7) & 7) << 4);
        }

    // staging source offsets (elements): raw = b ^ s(b), row=raw>>6, col=(raw&63)>>1
    size_t goffA0, goffA1, goffB;
    {
        u32 b0 = (u32)tid * 16;
        u32 r0 = b0 ^ (((b0 >> 7) & 7) << 4);
        goffA0 = (size_t)(r0 >> 6) * E_DIM + ((r0 & 63) >> 1);
        u32 b1 = (u32)(tid + 512) * 16;
        u32 r1 = b1 ^ (((b1 >> 7) & 7) << 4);
        goffA1 = (size_t)(r1 >> 6) * E_DIM + ((r1 & 63) >> 1);
        goffB = (size_t)(r0 >> 6) * E_DIM + ((r0 & 63) >> 1);   // B rows 0..127 (b0<8192)
    }

    const u16* Ag = A + (size_t)tm * E_DIM;
    const u16* Bg = Bt + (size_t)tn * E_DIM;

    f32x16 acc[4] = {};

    // ---- prologue: stage k=0 -> slot0, k=1 -> slot1 (order A,A,B per slot) ----
    gload_lds16(Ag + goffA0, &Als[0][tid * 8]);
    gload_lds16(Ag + goffA1, &Als[0][(tid + 512) * 8]);
    gload_lds16(Bg + goffB, &Bls[0][tid * 8]);
    gload_lds16(Ag + goffA0 + 32, &Als[1][tid * 8]);
    gload_lds16(Ag + goffA1 + 32, &Als[1][(tid + 512) * 8]);
    gload_lds16(Bg + goffB + 32, &Bls[1][tid * 8]);
    asm volatile("s_waitcnt vmcnt(3)" ::: "memory");   // slot0 landed; slot1 in flight
    __builtin_amdgcn_sched_barrier(0);
    __builtin_amdgcn_s_barrier();

    // ---- K loop: 32 steps of BK=32; stage(k+2) issued, vmcnt(3) retires stage(k+1) ----
    for (int k = 0; k < 32; k++) {
        const int sl = k - (k / 3) * 3;            // k % 3
        const int sp = (k + 2) - ((k + 2) / 3) * 3;
        // stage(k+2) (unconditional; tail reads land in adjacent ws allocations)
        const size_t ko = (size_t)(k + 2) * 32;
        gload_lds16(Ag + goffA0 + ko, &Als[sp][tid * 8]);
        gload_lds16(Ag + goffA1 + ko, &Als[sp][(tid + 512) * 8]);
        gload_lds16(Bg + goffB + ko, &Bls[sp][tid * 8]);

        // compute slot sl
        const char* Ab = (const char*)Als[sl];
        const char* Bb = (const char*)Bls[sl];
        __builtin_amdgcn_s_setprio(1);
        #pragma unroll
        for (int ks = 0; ks < 2; ks++) {
            const bf16x8 af = *(const bf16x8*)(Ab + aoff[ks]);
            #pragma unroll
            for (int nt = 0; nt < 4; nt++) {
                const bf16x8 bt = *(const bf16x8*)(Bb + boff[nt][ks]);
                acc[nt] = MFMA32(bt, af, acc[nt]);
            }
        }
        __builtin_amdgcn_s_setprio(0);

        asm volatile("s_waitcnt vmcnt(3)" ::: "memory");   // stage(k+1) retired
        __builtin_amdgcn_sched_barrier(0);
        __builtin_amdgcn_s_barrier();
    }

    // ---- epilogue: bias + scale, bf16 C write (block is within one weight slice) ----
    const int slice = tn >> 10;
    const float* bias = (slice == 0) ? bias0 : (slice == 1 ? bias1 : bias2);
    const float scale = (slice == 0) ? scale0 : 1.0f;
    const int m = tm + w * 32 + l31;
    const int cb = tn & 1023;
    u16* C = Cb + (size_t)slice * ((size_t)M_TOT * E_DIM) + (size_t)m * E_DIM + cb;
    #pragma unroll
    for (int nt = 0; nt < 4; nt++) {
        #pragma unroll
        for (int oct = 0; oct < 2; oct++) {
            const int nb = nt * 32 + oct * 16 + hi * 8;
            const f32x4 bv0 = *reinterpret_cast<const f32x4*>(bias + cb + nb);
            const f32x4 bv1 = *reinterpret_cast<const f32x4*>(bias + cb + nb + 4);
            const int r0 = oct * 8;
            u32x4 pk;
            pk[0] = cvt_pk_bf16((acc[nt][r0 + 0] + bv0[0]) * scale,
                                (acc[nt][r0 + 1] + bv0[1]) * scale);
            pk[1] = cvt_pk_bf16((acc[nt][r0 + 2] + bv0[2]) * scale,
                                (acc[nt][r0 + 3] + bv0[3]) * scale);
            pk[2] = cvt_pk_bf16((acc[nt][r0 + 4] + bv1[0]) * scale,
                                (acc[nt][r0 + 5] + bv1[1]) * scale);
            pk[3] = cvt_pk_bf16((acc[nt][r0 + 6] + bv1[2]) * scale,
                                (acc[nt][r0 + 7] + bv1[3]) * scale);
            *reinterpret_cast<u32x4*>(C + nb) = pk;
        }
    }
}

// ---------------- flash attention: R13-verified (pipelined, 2 q-tiles/block) ----------------
__global__ __launch_bounds__(512) void attn_kernel(
    const u16* __restrict__ Q, const u16* __restrict__ K, const u16* __restrict__ V,
    const u64* __restrict__ mbits, u16* __restrict__ PO, float* __restrict__ lws) {
    __shared__ __align__(16) u16 Kls[4][64 * 64];   // 32KB ring, slot stride 8192B
    __shared__ __align__(16) u16 Vt[2][64 * 64];    // 16KB dbuf, slot stride 8192B

    const int tid = threadIdx.x;          // 0..511
    const int lane = tid & 63;
    const int wave = tid >> 6;            // 0..7
    const int sub = wave >> 2;
    const int wg = wave & 3;
    const int hi = lane >> 5;
    const int l31 = lane & 31;
    const int n = blockIdx.x;
    const int g = n & 63, qt = n >> 6;
    const int h = g & 15, zz = g >> 4;
    const int b = zz >> 1, half = zz & 1;

    const int qrow = b * SEQ + qt * 256 + sub * 128 + wg * 32 + l31;
    bf16x8 qf[4];
    #pragma unroll
    for (int kc = 0; kc < 4; kc++)
        qf[kc] = *reinterpret_cast<const bf16x8*>(Q + (size_t)qrow * E_DIM + h * DH + kc * 16 + hi * 8);

    const int krow = (l31 & 3) | ((l31 & 4) << 1) | ((l31 & 8) >> 1) | (l31 & 16);
    const u32 ksw = (u32)(krow & 7) << 4;
    u32 koff[4];
    #pragma unroll
    for (int kc = 0; kc < 4; kc++)
        koff[kc] = (((u32)krow * 128) + (u32)kc * 32 + (u32)hi * 16) ^ ksw;

    const int krA = tid >> 3;
    const int kcA = (tid & 7) ^ (krA & 7);
    const size_t kgoff = (size_t)krA * E_DIM + kcA * 8;

    const int t8 = tid & 255;
    const int vhalf = tid >> 8;
    const int vc = t8 & 7;
    const int vsg = ((t8 >> 3) ^ (vc << 2)) & 31;
    const size_t vgoff = (size_t)(2 * vsg) * E_DIM + vc * 8 + vhalf * 4;
    u32 vwoff[4];
    #pragma unroll
    for (int jj = 0; jj < 4; jj++) {
        const int j = vhalf * 4 + jj;
        vwoff[jj] = (((u32)(vc * 8 + j) * 128) + (u32)vsg * 4) ^ ((u32)j << 4);
    }
    u32 vroff[4];
    #pragma unroll
    for (int kc = 0; kc < 4; kc++)
        vroff[kc] = (((u32)l31 * 128) + (u32)(2 * kc + hi) * 16) ^ (((u32)(l31 & 7)) << 4);

    f32x16 oacc0 = {}, oacc1 = {};
    float l_run = 0.f;

    const u16* Kg = K + (size_t)(b * SEQ + half * (SEQ / 2)) * E_DIM + h * DH;
    const u16* Vg = V + (size_t)(b * SEQ + half * (SEQ / 2)) * E_DIM + h * DH;
    const size_t TSTEP = (size_t)64 * E_DIM;
    const u16* kgp = Kg + kgoff;
    const u16* vgp = Vg + vgoff;
    const int NT = SEQ / 2 / 64;   // 16

    {
        u32x2 a0 = *reinterpret_cast<const u32x2*>(vgp);
        u32x2 a1 = *reinterpret_cast<const u32x2*>(vgp + E_DIM);
        gload_lds16(kgp,             &Kls[0][tid * 8]);
        gload_lds16(kgp + TSTEP,     &Kls[1][tid * 8]);
        gload_lds16(kgp + 2 * TSTEP, &Kls[2][tid * 8]);
        kgp += 3 * TSTEP; vgp += TSTEP;
        asm volatile("s_waitcnt vmcnt(1)" ::: "memory");
        __builtin_amdgcn_sched_barrier(0);
        #pragma unroll
        for (int jj = 0; jj < 4; jj++)
            *(u32*)((char*)Vt + vwoff[jj]) = __builtin_amdgcn_perm(
                a1[jj >> 1], a0[jj >> 1], (jj & 1) ? 0x07060302u : 0x05040100u);
        asm volatile("s_waitcnt lgkmcnt(0)" ::: "memory");
        __builtin_amdgcn_sched_barrier(0);
        __builtin_amdgcn_s_barrier();
    }

    f32x16 sc0 = {}, sc1 = {};
    {
        const char* Kb = (const char*)Kls;
        __builtin_amdgcn_s_setprio(1);
        #pragma unroll
        for (int kc = 0; kc < 4; kc++) {
            bf16x8 kf0 = *(const bf16x8*)(Kb + koff[kc]);
            bf16x8 kf1 = *(const bf16x8*)(Kb + koff[kc] + 4096);
            sc0 = MFMA32(kf0, qf[kc], sc0);
            sc1 = MFMA32(kf1, qf[kc], sc1);
        }
        __builtin_amdgcn_s_setprio(0);
    }

    for (int t = 0; t < NT; t++) {
        const bool haveV = (t + 1 < NT);
        const bool haveK = (t + 3 < NT);
        u32x2 a0, a1;
        if (haveV) {
            a0 = *reinterpret_cast<const u32x2*>(vgp);
            a1 = *reinterpret_cast<const u32x2*>(vgp + E_DIM);
        }
        if (haveK) {
            gload_lds16(kgp, &Kls[(t + 3) & 3][tid * 8]);
        }

        const u64 mb = mbits[b * (SEQ / 64) + half * NT + t];
        if (mb != ~0ull) {
            #pragma unroll
            for (int r = 0; r < 16; r++) {
                const int key = (r & 3) + 4 * ((r >> 2) & 1) + 8 * hi + 16 * ((r >> 3) & 1);
                if (!((mb >> key) & 1))        sc0[r] += -1.442695e9f;
                if (!((mb >> (32 + key)) & 1)) sc1[r] += -1.442695e9f;
            }
        }
        float sum = 0.f;
        #pragma unroll
        for (int r = 0; r < 16; r++) {
            sc0[r] = __builtin_amdgcn_exp2f(sc0[r]); sum += sc0[r];
        }
        #pragma unroll
        for (int r = 0; r < 16; r++) {
            sc1[r] = __builtin_amdgcn_exp2f(sc1[r]); sum += sc1[r];
        }
        l_run += sum;

        bf16x8 pf[4];
        {
            u32x4 pw0, pw1, pw2, pw3;
            #pragma unroll
            for (int e = 0; e < 4; e++) {
                pw0[e] = cvt_pk_bf16(sc0[2 * e],     sc0[2 * e + 1]);
                pw1[e] = cvt_pk_bf16(sc0[8 + 2 * e], sc0[9 + 2 * e]);
                pw2[e] = cvt_pk_bf16(sc1[2 * e],     sc1[2 * e + 1]);
                pw3[e] = cvt_pk_bf16(sc1[8 + 2 * e], sc1[9 + 2 * e]);
            }
            pf[0] = __builtin_bit_cast(bf16x8, pw0);
            pf[1] = __builtin_bit_cast(bf16x8, pw1);
            pf[2] = __builtin_bit_cast(bf16x8, pw2);
            pf[3] = __builtin_bit_cast(bf16x8, pw3);
        }

        f32x16 sn0 = {}, sn1 = {};
        if (haveV) {
            const char* Kb = (const char*)Kls + ((t + 1) & 3) * 8192;
            __builtin_amdgcn_s_setprio(1);
            #pragma unroll
            for (int kc = 0; kc < 4; kc++) {
                bf16x8 kf0 = *(const bf16x8*)(Kb + koff[kc]);
                bf16x8 kf1 = *(const bf16x8*)(Kb + koff[kc] + 4096);
                sn0 = MFMA32(kf0, qf[kc], sn0);
                sn1 = MFMA32(kf1, qf[kc], sn1);
            }
            __builtin_amdgcn_s_setprio(0);
        }

        {
            const char* Vb = (const char*)Vt + (t & 1) * 8192;
            __builtin_amdgcn_s_setprio(1);
            #pragma unroll
            for (int kc = 0; kc < 4; kc++) {
                bf16x8 vf0 = *(const bf16x8*)(Vb + vroff[kc]);
                bf16x8 vf1 = *(const bf16x8*)(Vb + vroff[kc] + 4096);
                oacc0 = MFMA32(vf0, pf[kc], oacc0);
                oacc1 = MFMA32(vf1, pf[kc], oacc1);
            }
            __builtin_amdgcn_s_setprio(0);
        }

        asm volatile("s_waitcnt vmcnt(1)" ::: "memory");
        __builtin_amdgcn_sched_barrier(0);
        if (haveV) {
            #pragma unroll
            for (int jj = 0; jj < 4; jj++)
                *(u32*)((char*)Vt + ((t + 1) & 1) * 8192 + vwoff[jj]) = __builtin_amdgcn_perm(
                    a1[jj >> 1], a0[jj >> 1], (jj & 1) ? 0x07060302u : 0x05040100u);
        }
        asm volatile("s_waitcnt lgkmcnt(0)" ::: "memory");
        __builtin_amdgcn_sched_barrier(0);
        __builtin_amdgcn_s_barrier();

        sc0 = sn0; sc1 = sn1;
        if (haveK) { kgp += TSTEP; }
        if (haveV) { vgp += TSTEP; }
    }

    const float l_tot = l_run + __shfl_xor(l_run, 32);
    u16* op = PO + ((size_t)half * M_TOT + qrow) * E_DIM + h * DH;
    #pragma unroll
    for (int db = 0; db < 2; db++) {
        #pragma unroll
        for (int j = 0; j < 4; j++) {
            u32x2 pk;
            pk[0] = cvt_pk_bf16(db ? oacc1[4 * j + 0] : oacc0[4 * j + 0],
                                db ? oacc1[4 * j + 1] : oacc0[4 * j + 1]);
            pk[1] = cvt_pk_bf16(db ? oacc1[4 * j + 2] : oacc0[4 * j + 2],
                                db ? oacc1[4 * j + 3] : oacc0[4 * j + 3]);
            const int d0 = 32 * db + 8 * j + 4 * hi;
            *reinterpret_cast<u32x2*>(op + d0) = pk;
        }
    }
    if (hi == 0) lws[((size_t)half * M_TOT + qrow) * HNUM + h] = l_tot;
}

// ---------------- combine partials: ab = (PO0 + PO1) / (l0 + l1) ----------------
__global__ __launch_bounds__(256) void combine_kernel(const u16* __restrict__ PO,
                                                      const float* __restrict__ lws,
                                                      u16* __restrict__ ab) {
    const int i = (blockIdx.x * 256 + threadIdx.x) * 8;
    const int row = i >> 10;
    const int h = (i & 1023) >> 6;
    const float l0 = lws[(size_t)row * HNUM + h];
    const float l1 = lws[((size_t)M_TOT + row) * HNUM + h];
    const float rl = 1.0f / (l0 + l1);
    const bf16x8 a = *reinterpret_cast<const bf16x8*>(PO + i);
    const bf16x8 c = *reinterpret_cast<const bf16x8*>(PO + (size_t)M_TOT * E_DIM + i);
    u16x8 o;
    #pragma unroll
    for (int j = 0; j < 8; j++)
        o[j] = f2bf(((float)a[j] + (float)c[j]) * rl);
    *reinterpret_cast<u16x8*>(ab + i) = o;
}

extern "C" void kernel_launch(void* const* d_in, const int* in_sizes, int n_in,
                              void* d_out, int out_size, void* d_ws, size_t ws_size,
                              hipStream_t stream) {
    const float* x  = (const float*)d_in[0];
    const int* mask = (const int*)d_in[1];
    const float* Wq = (const float*)d_in[2];
    const float* bq = (const float*)d_in[3];
    const float* Wk = (const float*)d_in[4];
    const float* bk = (const float*)d_in[5];
    const float* Wv = (const float*)d_in[6];
    const float* bv = (const float*)d_in[7];
    const float* Wo = (const float*)d_in[8];
    const float* bo = (const float*)d_in[9];
    float* out = (float*)d_out;

    u16* ws  = (u16*)d_ws;
    const size_t ME = (size_t)M_TOT * E_DIM;         // 4194304
    u16* xb  = ws;                                   // [M][E] bf16 x ; later reused as ab
    u16* wt  = ws + ME;                              // 4x [E][E] bf16 W^T (q,k,v,o)
    u16* qb  = ws + 2 * ME;                          // Q,K,V contiguous [3][M][E]
    u16* kbf = ws + 3 * ME;
    u16* vbf = ws + 4 * ME;
    u64* mbf = (u64*)(ws + 5 * ME);                  // 64 u64 mask bitmaps (512B)
    float* lws = (float*)(ws + 5 * ME + 8192);       // [2][M][H] f32 l-partials (512KB)
    u16* ab  = xb;                                   // attn concat aliases xb
    u16* po  = (u16*)d_out;                          // partial O scratch: 2x[M][E] bf16 = 16MB

    cast_x_kernel<<<dim3(M_TOT * E_DIM / 1024), dim3(256), 0, stream>>>(x, xb, M_TOT * E_DIM);
    wtrans_kernel<<<dim3(E_DIM / 32, E_DIM / 32, 4), dim3(32, 8), 0, stream>>>(Wq, Wk, Wv, Wo, wt);
    maskbits_kernel<<<dim3(M_TOT / 256), dim3(256), 0, stream>>>(mask, mbf);
    gemm256_kernel<<<dim3(M_TOT / 256, 3 * E_DIM / 128), dim3(512), 0, stream>>>(
        xb, wt, qb, bq, bk, bv, 0.125f * LOG2E);
    attn_kernel<<<dim3(512), dim3(512), 0, stream>>>(qb, kbf, vbf, mbf, po, lws);
    combine_kernel<<<dim3(M_TOT * E_DIM / 2048), dim3(256), 0, stream>>>(po, lws, ab);
    gemm_kernel<float><<<dim3(E_DIM / 128, M_TOT / 128, 1), dim3(256), 0, stream>>>(
        ab, wt + (size_t)3 * E_DIM * E_DIM, out, bo, bo, bo, 1.0f, M_TOT);
}

// Round 16
// 126.896 us; speedup vs baseline: 1.0743x; 1.0743x over previous
//
#include <hip/hip_runtime.h>
#include <stdint.h>

#define E_DIM   1024
#define HNUM    16
#define DH      64
#define BATCH   2
#define SEQ     2048
#define M_TOT   (BATCH*SEQ)   // 4096
#define LOG2E   1.44269504088896340736f

typedef __bf16 bf16x8 __attribute__((ext_vector_type(8)));
typedef __bf16 bf16x4 __attribute__((ext_vector_type(4)));
typedef float  f32x4  __attribute__((ext_vector_type(4)));
typedef float  f32x16 __attribute__((ext_vector_type(16)));
typedef unsigned short u16;
typedef unsigned int   u32;
typedef unsigned long long u64;
typedef u16 u16x8 __attribute__((ext_vector_type(8)));
typedef u32 u32x2 __attribute__((ext_vector_type(2)));
typedef u32 u32x4 __attribute__((ext_vector_type(4)));

__device__ __forceinline__ u16 f2bf(float f) {
    u32 u = __builtin_bit_cast(u32, f);
    u32 r = 0x7FFFu + ((u >> 16) & 1u);
    return (u16)((u + r) >> 16);
}

__device__ __forceinline__ void gload_lds16(const u16* g, u16* l) {
    __builtin_amdgcn_global_load_lds(
        (const __attribute__((address_space(1))) u32*)g,
        (__attribute__((address_space(3))) u32*)l, 16, 0, 0);
}

__device__ __forceinline__ u32 cvt_pk_bf16(float lo, float hi) {
    u32 r;
    asm("v_cvt_pk_bf16_f32 %0, %1, %2" : "=v"(r) : "v"(lo), "v"(hi));
    return r;
}

#define MFMA16(a,b,c) __builtin_amdgcn_mfma_f32_16x16x32_bf16((a),(b),(c),0,0,0)
#define MFMA32(a,b,c) __builtin_amdgcn_mfma_f32_32x32x16_bf16((a),(b),(c),0,0,0)

// ---------------- cast x (fp32 -> bf16) + fold-in mask bitmaps ----------------
__global__ __launch_bounds__(256) void cast_x_kernel(const float* __restrict__ x,
                                                     u16* __restrict__ out,
                                                     const int* __restrict__ mask,
                                                     u64* __restrict__ bits, int n) {
    int idx = (blockIdx.x * 256 + threadIdx.x) * 4;
    if (idx < n) {
        float4 v = *reinterpret_cast<const float4*>(x + idx);
        ushort4 o;
        o.x = f2bf(v.x); o.y = f2bf(v.y); o.z = f2bf(v.z); o.w = f2bf(v.w);
        *reinterpret_cast<ushort4*>(out + idx) = o;
    }
    if (blockIdx.x < M_TOT / 256) {
        int i = blockIdx.x * 256 + threadIdx.x;
        u64 bl = __ballot(mask[i] != 0);
        if ((i & 63) == 0) bits[i >> 6] = bl;
    }
}

// ---------------- weight transpose + cast: Wt[n][k] = bf16(W[k][n]) ----------------
__global__ void wtrans_kernel(const float* __restrict__ w0, const float* __restrict__ w1,
                              const float* __restrict__ w2, const float* __restrict__ w3,
                              u16* __restrict__ out) {
    __shared__ float tile[32][33];
    const float* w = blockIdx.z == 0 ? w0 : blockIdx.z == 1 ? w1 : blockIdx.z == 2 ? w2 : w3;
    const int n0 = blockIdx.x * 32, k0 = blockIdx.y * 32;
    #pragma unroll
    for (int j = 0; j < 4; j++) {
        int k = k0 + threadIdx.y + j * 8;
        tile[threadIdx.y + j * 8][threadIdx.x] = w[(size_t)k * E_DIM + n0 + threadIdx.x];
    }
    __syncthreads();
    u16* o = out + (size_t)blockIdx.z * E_DIM * E_DIM;
    #pragma unroll
    for (int j = 0; j < 4; j++) {
        int n = n0 + threadIdx.y + j * 8;
        o[(size_t)n * E_DIM + k0 + threadIdx.x] = f2bf(tile[threadIdx.x][threadIdx.y + j * 8]);
    }
}

// ---------------- GEMM: C[z] = A @ Wt[z]^T + bias[z], scale on z==0 ----------------
template <typename OutT>
__global__ __launch_bounds__(256) void gemm_kernel(
    const u16* __restrict__ A, const u16* __restrict__ Bt_base, OutT* __restrict__ C_base,
    const float* __restrict__ bias0, const float* __restrict__ bias1,
    const float* __restrict__ bias2, float scale0, int Mdim) {
    const int z = blockIdx.z;
    const u16* Bt = Bt_base + (size_t)z * E_DIM * E_DIM;
    OutT* C = C_base + (size_t)z * Mdim * E_DIM;
    const float* bias = (z == 0) ? bias0 : (z == 1 ? bias1 : bias2);
    const float scale = (z == 0) ? scale0 : 1.0f;

    __shared__ __align__(16) u16 Als[128 * 32];
    __shared__ __align__(16) u16 Bls[128 * 32];

    const int tid = threadIdx.x;
    const int lane = tid & 63;
    const int w = tid >> 6;
    const int wr = (w >> 1) * 64, wc = (w & 1) * 64;
    const int tm = blockIdx.y * 128, tn = blockIdx.x * 128;
    const int r4 = tid >> 2;
    const int c8 = (tid & 3) * 8;

    f32x4 acc[4][4] = {};

    for (int k0 = 0; k0 < E_DIM; k0 += 32) {
        gload_lds16(A + (size_t)(tm + r4) * E_DIM + k0 + c8, Als + tid * 8);
        gload_lds16(A + (size_t)(tm + 64 + r4) * E_DIM + k0 + c8, Als + 2048 + tid * 8);
        gload_lds16(Bt + (size_t)(tn + r4) * E_DIM + k0 + c8, Bls + tid * 8);
        gload_lds16(Bt + (size_t)(tn + 64 + r4) * E_DIM + k0 + c8, Bls + 2048 + tid * 8);
        __syncthreads();
        const int lr = lane & 15, lg = lane >> 4;
        bf16x8 af[4], bfr[4];
        #pragma unroll
        for (int m = 0; m < 4; m++)
            af[m] = *reinterpret_cast<const bf16x8*>(Als + (wr + m * 16 + lr) * 32 + lg * 8);
        #pragma unroll
        for (int n = 0; n < 4; n++)
            bfr[n] = *reinterpret_cast<const bf16x8*>(Bls + (wc + n * 16 + lr) * 32 + lg * 8);
        #pragma unroll
        for (int m = 0; m < 4; m++)
            #pragma unroll
            for (int n = 0; n < 4; n++)
                acc[m][n] = MFMA16(af[m], bfr[n], acc[m][n]);
        __syncthreads();
    }

    const int lr = lane & 15, lg = lane >> 4;
    #pragma unroll
    for (int m = 0; m < 4; m++) {
        #pragma unroll
        for (int n = 0; n < 4; n++) {
            const int col = tn + wc + n * 16 + lr;
            const float bv = bias[col];
            #pragma unroll
            for (int r = 0; r < 4; r++) {
                const int row = tm + wr + m * 16 + lg * 4 + r;
                float v = (acc[m][n][r] + bv) * scale;
                if constexpr (sizeof(OutT) == 2) {
                    C[(size_t)row * E_DIM + col] = f2bf(v);
                } else {
                    C[(size_t)row * E_DIM + col] = v;
                }
            }
        }
    }
}

// ---------------- flash attention: R13-verified (pipelined, 2 q-tiles/block) ----------------
// 512 blocks (XCD-local 1D: n&63 = (h,b,half) group, n>>6 = q-block of 256 rows).
// Waves 0-3 -> q-rows [0,128), waves 4-7 -> [128,256); ONE shared K/V stream per block.
// K: 4-slot LDS ring staged 3 ahead (ONE gload_lds/thread); per-tile s_waitcnt vmcnt(1)
// keeps K(t+3) in flight. V: reg-staged dbuf (issue-early/write-late). Per tile:
// softmax(s_cur) -> P -> QK(t+1) -> PV(t). Fixed-max exp2 softmax; key-split partials;
// Q pre-scaled by (1/sqrt(D))*log2(e).
__global__ __launch_bounds__(512) void attn_kernel(
    const u16* __restrict__ Q, const u16* __restrict__ K, const u16* __restrict__ V,
    const u64* __restrict__ mbits, u16* __restrict__ PO, float* __restrict__ lws) {
    __shared__ __align__(16) u16 Kls[4][64 * 64];   // 32KB ring, slot stride 8192B
    __shared__ __align__(16) u16 Vt[2][64 * 64];    // 16KB dbuf, slot stride 8192B

    const int tid = threadIdx.x;          // 0..511
    const int lane = tid & 63;
    const int wave = tid >> 6;            // 0..7
    const int sub = wave >> 2;
    const int wg = wave & 3;
    const int hi = lane >> 5;
    const int l31 = lane & 31;
    const int n = blockIdx.x;
    const int g = n & 63, qt = n >> 6;
    const int h = g & 15, zz = g >> 4;
    const int b = zz >> 1, half = zz & 1;

    const int qrow = b * SEQ + qt * 256 + sub * 128 + wg * 32 + l31;
    bf16x8 qf[4];
    #pragma unroll
    for (int kc = 0; kc < 4; kc++)
        qf[kc] = *reinterpret_cast<const bf16x8*>(Q + (size_t)qrow * E_DIM + h * DH + kc * 16 + hi * 8);

    const int krow = (l31 & 3) | ((l31 & 4) << 1) | ((l31 & 8) >> 1) | (l31 & 16);
    const u32 ksw = (u32)(krow & 7) << 4;
    u32 koff[4];
    #pragma unroll
    for (int kc = 0; kc < 4; kc++)
        koff[kc] = (((u32)krow * 128) + (u32)kc * 32 + (u32)hi * 16) ^ ksw;

    const int krA = tid >> 3;
    const int kcA = (tid & 7) ^ (krA & 7);
    const size_t kgoff = (size_t)krA * E_DIM + kcA * 8;

    const int t8 = tid & 255;
    const int vhalf = tid >> 8;
    const int vc = t8 & 7;
    const int vsg = ((t8 >> 3) ^ (vc << 2)) & 31;
    const size_t vgoff = (size_t)(2 * vsg) * E_DIM + vc * 8 + vhalf * 4;
    u32 vwoff[4];
    #pragma unroll
    for (int jj = 0; jj < 4; jj++) {
        const int j = vhalf * 4 + jj;
        vwoff[jj] = (((u32)(vc * 8 + j) * 128) + (u32)vsg * 4) ^ ((u32)j << 4);
    }
    u32 vroff[4];
    #pragma unroll
    for (int kc = 0; kc < 4; kc++)
        vroff[kc] = (((u32)l31 * 128) + (u32)(2 * kc + hi) * 16) ^ (((u32)(l31 & 7)) << 4);

    f32x16 oacc0 = {}, oacc1 = {};
    float l_run = 0.f;

    const u16* Kg = K + (size_t)(b * SEQ + half * (SEQ / 2)) * E_DIM + h * DH;
    const u16* Vg = V + (size_t)(b * SEQ + half * (SEQ / 2)) * E_DIM + h * DH;
    const size_t TSTEP = (size_t)64 * E_DIM;
    const u16* kgp = Kg + kgoff;
    const u16* vgp = Vg + vgoff;
    const int NT = SEQ / 2 / 64;   // 16

    {
        u32x2 a0 = *reinterpret_cast<const u32x2*>(vgp);
        u32x2 a1 = *reinterpret_cast<const u32x2*>(vgp + E_DIM);
        gload_lds16(kgp,             &Kls[0][tid * 8]);
        gload_lds16(kgp + TSTEP,     &Kls[1][tid * 8]);
        gload_lds16(kgp + 2 * TSTEP, &Kls[2][tid * 8]);
        kgp += 3 * TSTEP; vgp += TSTEP;
        asm volatile("s_waitcnt vmcnt(1)" ::: "memory");
        __builtin_amdgcn_sched_barrier(0);
        #pragma unroll
        for (int jj = 0; jj < 4; jj++)
            *(u32*)((char*)Vt + vwoff[jj]) = __builtin_amdgcn_perm(
                a1[jj >> 1], a0[jj >> 1], (jj & 1) ? 0x07060302u : 0x05040100u);
        asm volatile("s_waitcnt lgkmcnt(0)" ::: "memory");
        __builtin_amdgcn_sched_barrier(0);
        __builtin_amdgcn_s_barrier();
    }

    f32x16 sc0 = {}, sc1 = {};
    {
        const char* Kb = (const char*)Kls;
        __builtin_amdgcn_s_setprio(1);
        #pragma unroll
        for (int kc = 0; kc < 4; kc++) {
            bf16x8 kf0 = *(const bf16x8*)(Kb + koff[kc]);
            bf16x8 kf1 = *(const bf16x8*)(Kb + koff[kc] + 4096);
            sc0 = MFMA32(kf0, qf[kc], sc0);
            sc1 = MFMA32(kf1, qf[kc], sc1);
        }
        __builtin_amdgcn_s_setprio(0);
    }

    for (int t = 0; t < NT; t++) {
        const bool haveV = (t + 1 < NT);
        const bool haveK = (t + 3 < NT);
        u32x2 a0, a1;
        if (haveV) {
            a0 = *reinterpret_cast<const u32x2*>(vgp);
            a1 = *reinterpret_cast<const u32x2*>(vgp + E_DIM);
        }
        if (haveK) {
            gload_lds16(kgp, &Kls[(t + 3) & 3][tid * 8]);
        }

        const u64 mb = mbits[b * (SEQ / 64) + half * NT + t];
        if (mb != ~0ull) {
            #pragma unroll
            for (int r = 0; r < 16; r++) {
                const int key = (r & 3) + 4 * ((r >> 2) & 1) + 8 * hi + 16 * ((r >> 3) & 1);
                if (!((mb >> key) & 1))        sc0[r] += -1.442695e9f;
                if (!((mb >> (32 + key)) & 1)) sc1[r] += -1.442695e9f;
            }
        }
        float sum = 0.f;
        #pragma unroll
        for (int r = 0; r < 16; r++) {
            sc0[r] = __builtin_amdgcn_exp2f(sc0[r]); sum += sc0[r];
        }
        #pragma unroll
        for (int r = 0; r < 16; r++) {
            sc1[r] = __builtin_amdgcn_exp2f(sc1[r]); sum += sc1[r];
        }
        l_run += sum;

        bf16x8 pf[4];
        {
            u32x4 pw0, pw1, pw2, pw3;
            #pragma unroll
            for (int e = 0; e < 4; e++) {
                pw0[e] = cvt_pk_bf16(sc0[2 * e],     sc0[2 * e + 1]);
                pw1[e] = cvt_pk_bf16(sc0[8 + 2 * e], sc0[9 + 2 * e]);
                pw2[e] = cvt_pk_bf16(sc1[2 * e],     sc1[2 * e + 1]);
                pw3[e] = cvt_pk_bf16(sc1[8 + 2 * e], sc1[9 + 2 * e]);
            }
            pf[0] = __builtin_bit_cast(bf16x8, pw0);
            pf[1] = __builtin_bit_cast(bf16x8, pw1);
            pf[2] = __builtin_bit_cast(bf16x8, pw2);
            pf[3] = __builtin_bit_cast(bf16x8, pw3);
        }

        f32x16 sn0 = {}, sn1 = {};
        if (haveV) {
            const char* Kb = (const char*)Kls + ((t + 1) & 3) * 8192;
            __builtin_amdgcn_s_setprio(1);
            #pragma unroll
            for (int kc = 0; kc < 4; kc++) {
                bf16x8 kf0 = *(const bf16x8*)(Kb + koff[kc]);
                bf16x8 kf1 = *(const bf16x8*)(Kb + koff[kc] + 4096);
                sn0 = MFMA32(kf0, qf[kc], sn0);
                sn1 = MFMA32(kf1, qf[kc], sn1);
            }
            __builtin_amdgcn_s_setprio(0);
        }

        {
            const char* Vb = (const char*)Vt + (t & 1) * 8192;
            __builtin_amdgcn_s_setprio(1);
            #pragma unroll
            for (int kc = 0; kc < 4; kc++) {
                bf16x8 vf0 = *(const bf16x8*)(Vb + vroff[kc]);
                bf16x8 vf1 = *(const bf16x8*)(Vb + vroff[kc] + 4096);
                oacc0 = MFMA32(vf0, pf[kc], oacc0);
                oacc1 = MFMA32(vf1, pf[kc], oacc1);
            }
            __builtin_amdgcn_s_setprio(0);
        }

        asm volatile("s_waitcnt vmcnt(1)" ::: "memory");
        __builtin_amdgcn_sched_barrier(0);
        if (haveV) {
            #pragma unroll
            for (int jj = 0; jj < 4; jj++)
                *(u32*)((char*)Vt + ((t + 1) & 1) * 8192 + vwoff[jj]) = __builtin_amdgcn_perm(
                    a1[jj >> 1], a0[jj >> 1], (jj & 1) ? 0x07060302u : 0x05040100u);
        }
        asm volatile("s_waitcnt lgkmcnt(0)" ::: "memory");
        __builtin_amdgcn_sched_barrier(0);
        __builtin_amdgcn_s_barrier();

        sc0 = sn0; sc1 = sn1;
        if (haveK) { kgp += TSTEP; }
        if (haveV) { vgp += TSTEP; }
    }

    const float l_tot = l_run + __shfl_xor(l_run, 32);
    u16* op = PO + ((size_t)half * M_TOT + qrow) * E_DIM + h * DH;
    #pragma unroll
    for (int db = 0; db < 2; db++) {
        #pragma unroll
        for (int j = 0; j < 4; j++) {
            u32x2 pk;
            pk[0] = cvt_pk_bf16(db ? oacc1[4 * j + 0] : oacc0[4 * j + 0],
                                db ? oacc1[4 * j + 1] : oacc0[4 * j + 1]);
            pk[1] = cvt_pk_bf16(db ? oacc1[4 * j + 2] : oacc0[4 * j + 2],
                                db ? oacc1[4 * j + 3] : oacc0[4 * j + 3]);
            const int d0 = 32 * db + 8 * j + 4 * hi;
            *reinterpret_cast<u32x2*>(op + d0) = pk;
        }
    }
    if (hi == 0) lws[((size_t)half * M_TOT + qrow) * HNUM + h] = l_tot;
}

// ---------------- combine partials: ab = (PO0 + PO1) / (l0 + l1) ----------------
__global__ __launch_bounds__(256) void combine_kernel(const u16* __restrict__ PO,
                                                      const float* __restrict__ lws,
                                                      u16* __restrict__ ab) {
    const int i = (blockIdx.x * 256 + threadIdx.x) * 8;
    const int row = i >> 10;
    const int h = (i & 1023) >> 6;
    const float l0 = lws[(size_t)row * HNUM + h];
    const float l1 = lws[((size_t)M_TOT + row) * HNUM + h];
    const float rl = 1.0f / (l0 + l1);
    const bf16x8 a = *reinterpret_cast<const bf16x8*>(PO + i);
    const bf16x8 c = *reinterpret_cast<const bf16x8*>(PO + (size_t)M_TOT * E_DIM + i);
    u16x8 o;
    #pragma unroll
    for (int j = 0; j < 8; j++)
        o[j] = f2bf(((float)a[j] + (float)c[j]) * rl);
    *reinterpret_cast<u16x8*>(ab + i) = o;
}

extern "C" void kernel_launch(void* const* d_in, const int* in_sizes, int n_in,
                              void* d_out, int out_size, void* d_ws, size_t ws_size,
                              hipStream_t stream) {
    const float* x  = (const float*)d_in[0];
    const int* mask = (const int*)d_in[1];
    const float* Wq = (const float*)d_in[2];
    const float* bq = (const float*)d_in[3];
    const float* Wk = (const float*)d_in[4];
    const float* bk = (const float*)d_in[5];
    const float* Wv = (const float*)d_in[6];
    const float* bv = (const float*)d_in[7];
    const float* Wo = (const float*)d_in[8];
    const float* bo = (const float*)d_in[9];
    float* out = (float*)d_out;

    u16* ws  = (u16*)d_ws;
    const size_t ME = (size_t)M_TOT * E_DIM;         // 4194304
    u16* xb  = ws;                                   // [M][E] bf16 x ; later reused as ab
    u16* wt  = ws + ME;                              // 4x [E][E] bf16 W^T (q,k,v,o)
    u16* qb  = ws + 2 * ME;                          // Q,K,V contiguous [3][M][E]
    u16* kbf = ws + 3 * ME;
    u16* vbf = ws + 4 * ME;
    u64* mbf = (u64*)(ws + 5 * ME);                  // 64 u64 mask bitmaps (512B)
    float* lws = (float*)(ws + 5 * ME + 8192);       // [2][M][H] f32 l-partials (512KB)
    u16* ab  = xb;                                   // attn concat aliases xb
    u16* po  = (u16*)d_out;                          // partial O scratch: 2x[M][E] bf16 = 16MB

    cast_x_kernel<<<dim3(M_TOT * E_DIM / 1024), dim3(256), 0, stream>>>(
        x, xb, mask, mbf, M_TOT * E_DIM);
    wtrans_kernel<<<dim3(E_DIM / 32, E_DIM / 32, 4), dim3(32, 8), 0, stream>>>(Wq, Wk, Wv, Wo, wt);
    gemm_kernel<u16><<<dim3(E_DIM / 128, M_TOT / 128, 3), dim3(256), 0, stream>>>(
        xb, wt, qb, bq, bk, bv, 0.125f * LOG2E, M_TOT);
    attn_kernel<<<dim3(512), dim3(512), 0, stream>>>(qb, kbf, vbf, mbf, po, lws);
    combine_kernel<<<dim3(M_TOT * E_DIM / 2048), dim3(256), 0, stream>>>(po, lws, ab);
    gemm_kernel<float><<<dim3(E_DIM / 128, M_TOT / 128, 1), dim3(256), 0, stream>>>(
        ab, wt + (size_t)3 * E_DIM * E_DIM, out, bo, bo, bo, 1.0f, M_TOT);
}

// Round 17
// 122.751 us; speedup vs baseline: 1.1106x; 1.0338x over previous
//
#include <hip/hip_runtime.h>
#include <stdint.h>

#define E_DIM   1024
#define HNUM    16
#define DH      64
#define BATCH   2
#define SEQ     2048
#define M_TOT   (BATCH*SEQ)   // 4096
#define LOG2E   1.44269504088896340736f

typedef __bf16 bf16x8 __attribute__((ext_vector_type(8)));
typedef __bf16 bf16x4 __attribute__((ext_vector_type(4)));
typedef float  f32x4  __attribute__((ext_vector_type(4)));
typedef float  f32x16 __attribute__((ext_vector_type(16)));
typedef unsigned short u16;
typedef unsigned int   u32;
typedef unsigned long long u64;
typedef u16 u16x8 __attribute__((ext_vector_type(8)));
typedef u32 u32x2 __attribute__((ext_vector_type(2)));
typedef u32 u32x4 __attribute__((ext_vector_type(4)));

__device__ __forceinline__ u16 f2bf(float f) {
    u32 u = __builtin_bit_cast(u32, f);
    u32 r = 0x7FFFu + ((u >> 16) & 1u);
    return (u16)((u + r) >> 16);
}

__device__ __forceinline__ void gload_lds16(const u16* g, u16* l) {
    __builtin_amdgcn_global_load_lds(
        (const __attribute__((address_space(1))) u32*)g,
        (__attribute__((address_space(3))) u32*)l, 16, 0, 0);
}

__device__ __forceinline__ u32 cvt_pk_bf16(float lo, float hi) {
    u32 r;
    asm("v_cvt_pk_bf16_f32 %0, %1, %2" : "=v"(r) : "v"(lo), "v"(hi));
    return r;
}

#define MFMA16(a,b,c) __builtin_amdgcn_mfma_f32_16x16x32_bf16((a),(b),(c),0,0,0)
#define MFMA32(a,b,c) __builtin_amdgcn_mfma_f32_32x32x16_bf16((a),(b),(c),0,0,0)

// ---------------- prep: cast x + mask bitmaps + weight transpose (one launch) ----------------
// blocks [0,4096): cast 1024 f32 -> bf16 each (first 16 also build mask bitmaps).
// blocks [4096,8192): weight transpose+cast, 1 block per 32x32 tile of one of 4 weights.
__global__ __launch_bounds__(256) void prep_kernel(
    const float* __restrict__ x, u16* __restrict__ out,
    const int* __restrict__ mask, u64* __restrict__ bits,
    const float* __restrict__ w0, const float* __restrict__ w1,
    const float* __restrict__ w2, const float* __restrict__ w3,
    u16* __restrict__ wt) {
    __shared__ float tile[32][33];
    const int bid = blockIdx.x;
    const int tid = threadIdx.x;
    if (bid < M_TOT * E_DIM / 1024) {
        const int idx = (bid * 256 + tid) * 4;
        float4 v = *reinterpret_cast<const float4*>(x + idx);
        ushort4 o;
        o.x = f2bf(v.x); o.y = f2bf(v.y); o.z = f2bf(v.z); o.w = f2bf(v.w);
        *reinterpret_cast<ushort4*>(out + idx) = o;
        if (bid < M_TOT / 256) {
            const int i = bid * 256 + tid;
            u64 bl = __ballot(mask[i] != 0);
            if ((i & 63) == 0) bits[i >> 6] = bl;
        }
    } else {
        const int wb = bid - M_TOT * E_DIM / 1024;
        const int z = wb >> 10;
        const int rem = wb & 1023;
        const int n0 = (rem & 31) * 32, k0 = (rem >> 5) * 32;
        const int tx = tid & 31, ty = tid >> 5;
        const float* w = z == 0 ? w0 : z == 1 ? w1 : z == 2 ? w2 : w3;
        #pragma unroll
        for (int j = 0; j < 4; j++) {
            int k = k0 + ty + j * 8;
            tile[ty + j * 8][tx] = w[(size_t)k * E_DIM + n0 + tx];
        }
        __syncthreads();
        u16* o = wt + (size_t)z * E_DIM * E_DIM;
        #pragma unroll
        for (int j = 0; j < 4; j++) {
            int n = n0 + ty + j * 8;
            o[(size_t)n * E_DIM + k0 + tx] = f2bf(tile[tx][ty + j * 8]);
        }
    }
}

// ---------------- GEMM: C[z] = A @ Wt[z]^T + bias[z], scale on z==0 ----------------
template <typename OutT>
__global__ __launch_bounds__(256) void gemm_kernel(
    const u16* __restrict__ A, const u16* __restrict__ Bt_base, OutT* __restrict__ C_base,
    const float* __restrict__ bias0, const float* __restrict__ bias1,
    const float* __restrict__ bias2, float scale0, int Mdim) {
    const int z = blockIdx.z;
    const u16* Bt = Bt_base + (size_t)z * E_DIM * E_DIM;
    OutT* C = C_base + (size_t)z * Mdim * E_DIM;
    const float* bias = (z == 0) ? bias0 : (z == 1 ? bias1 : bias2);
    const float scale = (z == 0) ? scale0 : 1.0f;

    __shared__ __align__(16) u16 Als[128 * 32];
    __shared__ __align__(16) u16 Bls[128 * 32];

    const int tid = threadIdx.x;
    const int lane = tid & 63;
    const int w = tid >> 6;
    const int wr = (w >> 1) * 64, wc = (w & 1) * 64;
    const int tm = blockIdx.y * 128, tn = blockIdx.x * 128;
    const int r4 = tid >> 2;
    const int c8 = (tid & 3) * 8;

    f32x4 acc[4][4] = {};

    for (int k0 = 0; k0 < E_DIM; k0 += 32) {
        gload_lds16(A + (size_t)(tm + r4) * E_DIM + k0 + c8, Als + tid * 8);
        gload_lds16(A + (size_t)(tm + 64 + r4) * E_DIM + k0 + c8, Als + 2048 + tid * 8);
        gload_lds16(Bt + (size_t)(tn + r4) * E_DIM + k0 + c8, Bls + tid * 8);
        gload_lds16(Bt + (size_t)(tn + 64 + r4) * E_DIM + k0 + c8, Bls + 2048 + tid * 8);
        __syncthreads();
        const int lr = lane & 15, lg = lane >> 4;
        bf16x8 af[4], bfr[4];
        #pragma unroll
        for (int m = 0; m < 4; m++)
            af[m] = *reinterpret_cast<const bf16x8*>(Als + (wr + m * 16 + lr) * 32 + lg * 8);
        #pragma unroll
        for (int n = 0; n < 4; n++)
            bfr[n] = *reinterpret_cast<const bf16x8*>(Bls + (wc + n * 16 + lr) * 32 + lg * 8);
        #pragma unroll
        for (int m = 0; m < 4; m++)
            #pragma unroll
            for (int n = 0; n < 4; n++)
                acc[m][n] = MFMA16(af[m], bfr[n], acc[m][n]);
        __syncthreads();
    }

    const int lr = lane & 15, lg = lane >> 4;
    #pragma unroll
    for (int m = 0; m < 4; m++) {
        #pragma unroll
        for (int n = 0; n < 4; n++) {
            const int col = tn + wc + n * 16 + lr;
            const float bv = bias[col];
            #pragma unroll
            for (int r = 0; r < 4; r++) {
                const int row = tm + wr + m * 16 + lg * 4 + r;
                float v = (acc[m][n][r] + bv) * scale;
                if constexpr (sizeof(OutT) == 2) {
                    C[(size_t)row * E_DIM + col] = f2bf(v);
                } else {
                    C[(size_t)row * E_DIM + col] = v;
                }
            }
        }
    }
}

// ---------------- flash attention: R13 structure + ping-pong unroll + l4 partial sums ----
// 512 blocks (XCD-local 1D), 512 thr, waves 0-3/4-7 on two q-sub-tiles, shared K/V stream,
// key-split partials. K: 4-slot ring staged 3 ahead, per-tile vmcnt(1). V: reg-staged dbuf.
// Loop 2x-unrolled with role-swapped score registers (no sc=sn copies); per-tile sums go
// to 4 independent accumulator chains (no serial 32-deep FP add chain).
__global__ __launch_bounds__(512) void attn_kernel(
    const u16* __restrict__ Q, const u16* __restrict__ K, const u16* __restrict__ V,
    const u64* __restrict__ mbits, u16* __restrict__ PO, float* __restrict__ lws) {
    __shared__ __align__(16) u16 Kls[4][64 * 64];   // 32KB ring, slot stride 8192B
    __shared__ __align__(16) u16 Vt[2][64 * 64];    // 16KB dbuf, slot stride 8192B

    const int tid = threadIdx.x;          // 0..511
    const int lane = tid & 63;
    const int wave = tid >> 6;            // 0..7
    const int sub = wave >> 2;
    const int wg = wave & 3;
    const int hi = lane >> 5;
    const int l31 = lane & 31;
    const int n = blockIdx.x;
    const int g = n & 63, qt = n >> 6;
    const int h = g & 15, zz = g >> 4;
    const int b = zz >> 1, half = zz & 1;

    const int qrow = b * SEQ + qt * 256 + sub * 128 + wg * 32 + l31;
    bf16x8 qf[4];
    #pragma unroll
    for (int kc = 0; kc < 4; kc++)
        qf[kc] = *reinterpret_cast<const bf16x8*>(Q + (size_t)qrow * E_DIM + h * DH + kc * 16 + hi * 8);

    const int krow = (l31 & 3) | ((l31 & 4) << 1) | ((l31 & 8) >> 1) | (l31 & 16);
    const u32 ksw = (u32)(krow & 7) << 4;
    u32 koff[4];
    #pragma unroll
    for (int kc = 0; kc < 4; kc++)
        koff[kc] = (((u32)krow * 128) + (u32)kc * 32 + (u32)hi * 16) ^ ksw;

    const int krA = tid >> 3;
    const int kcA = (tid & 7) ^ (krA & 7);
    const size_t kgoff = (size_t)krA * E_DIM + kcA * 8;

    const int t8 = tid & 255;
    const int vhalf = tid >> 8;
    const int vc = t8 & 7;
    const int vsg = ((t8 >> 3) ^ (vc << 2)) & 31;
    const size_t vgoff = (size_t)(2 * vsg) * E_DIM + vc * 8 + vhalf * 4;
    u32 vwoff[4];
    #pragma unroll
    for (int jj = 0; jj < 4; jj++) {
        const int j = vhalf * 4 + jj;
        vwoff[jj] = (((u32)(vc * 8 + j) * 128) + (u32)vsg * 4) ^ ((u32)j << 4);
    }
    u32 vroff[4];
    #pragma unroll
    for (int kc = 0; kc < 4; kc++)
        vroff[kc] = (((u32)l31 * 128) + (u32)(2 * kc + hi) * 16) ^ (((u32)(l31 & 7)) << 4);

    f32x16 oacc0 = {}, oacc1 = {};
    f32x4 l4 = {};

    const u16* Kg = K + (size_t)(b * SEQ + half * (SEQ / 2)) * E_DIM + h * DH;
    const u16* Vg = V + (size_t)(b * SEQ + half * (SEQ / 2)) * E_DIM + h * DH;
    const size_t TSTEP = (size_t)64 * E_DIM;
    const u16* kgp = Kg + kgoff;
    const u16* vgp = Vg + vgoff;
    const int NT = SEQ / 2 / 64;   // 16

    {
        u32x2 a0 = *reinterpret_cast<const u32x2*>(vgp);
        u32x2 a1 = *reinterpret_cast<const u32x2*>(vgp + E_DIM);
        gload_lds16(kgp,             &Kls[0][tid * 8]);
        gload_lds16(kgp + TSTEP,     &Kls[1][tid * 8]);
        gload_lds16(kgp + 2 * TSTEP, &Kls[2][tid * 8]);
        kgp += 3 * TSTEP; vgp += TSTEP;
        asm volatile("s_waitcnt vmcnt(1)" ::: "memory");
        __builtin_amdgcn_sched_barrier(0);
        #pragma unroll
        for (int jj = 0; jj < 4; jj++)
            *(u32*)((char*)Vt + vwoff[jj]) = __builtin_amdgcn_perm(
                a1[jj >> 1], a0[jj >> 1], (jj & 1) ? 0x07060302u : 0x05040100u);
        asm volatile("s_waitcnt lgkmcnt(0)" ::: "memory");
        __builtin_amdgcn_sched_barrier(0);
        __builtin_amdgcn_s_barrier();
    }

    f32x16 sc0 = {}, sc1 = {}, sn0, sn1;
    {
        const char* Kb = (const char*)Kls;
        __builtin_amdgcn_s_setprio(1);
        #pragma unroll
        for (int kc = 0; kc < 4; kc++) {
            bf16x8 kf0 = *(const bf16x8*)(Kb + koff[kc]);
            bf16x8 kf1 = *(const bf16x8*)(Kb + koff[kc] + 4096);
            sc0 = MFMA32(kf0, qf[kc], sc0);
            sc1 = MFMA32(kf1, qf[kc], sc1);
        }
        __builtin_amdgcn_s_setprio(0);
    }

// tile body: CUR = score regs for tile T (consumed), NXT = score regs for tile T+1 (produced)
#define ATTN_TILE(T, CUR0, CUR1, NXT0, NXT1)                                           \
    {                                                                                  \
        const int t_ = (T);                                                            \
        const bool haveV = (t_ + 1 < NT);                                              \
        const bool haveK = (t_ + 3 < NT);                                              \
        u32x2 a0, a1;                                                                  \
        if (haveV) {                                                                   \
            a0 = *reinterpret_cast<const u32x2*>(vgp);                                 \
            a1 = *reinterpret_cast<const u32x2*>(vgp + E_DIM);                         \
        }                                                                              \
        if (haveK) gload_lds16(kgp, &Kls[(t_ + 3) & 3][tid * 8]);                      \
        const u64 mb = mbits[b * (SEQ / 64) + half * NT + t_];                         \
        if (mb != ~0ull) {                                                             \
            _Pragma("unroll")                                                          \
            for (int r = 0; r < 16; r++) {                                             \
                const int key = (r & 3) + 4 * ((r >> 2) & 1) + 8 * hi + 16 * ((r >> 3) & 1); \
                if (!((mb >> key) & 1))        CUR0[r] += -1.442695e9f;                \
                if (!((mb >> (32 + key)) & 1)) CUR1[r] += -1.442695e9f;                \
            }                                                                          \
        }                                                                              \
        _Pragma("unroll")                                                              \
        for (int r = 0; r < 16; r++) {                                                 \
            CUR0[r] = __builtin_amdgcn_exp2f(CUR0[r]); l4[r & 3] += CUR0[r];           \
        }                                                                              \
        _Pragma("unroll")                                                              \
        for (int r = 0; r < 16; r++) {                                                 \
            CUR1[r] = __builtin_amdgcn_exp2f(CUR1[r]); l4[r & 3] += CUR1[r];           \
        }                                                                              \
        bf16x8 pf[4];                                                                  \
        {                                                                              \
            u32x4 pw0, pw1, pw2, pw3;                                                  \
            _Pragma("unroll")                                                          \
            for (int e = 0; e < 4; e++) {                                              \
                pw0[e] = cvt_pk_bf16(CUR0[2 * e],     CUR0[2 * e + 1]);                \
                pw1[e] = cvt_pk_bf16(CUR0[8 + 2 * e], CUR0[9 + 2 * e]);                \
                pw2[e] = cvt_pk_bf16(CUR1[2 * e],     CUR1[2 * e + 1]);                \
                pw3[e] = cvt_pk_bf16(CUR1[8 + 2 * e], CUR1[9 + 2 * e]);                \
            }                                                                          \
            pf[0] = __builtin_bit_cast(bf16x8, pw0);                                   \
            pf[1] = __builtin_bit_cast(bf16x8, pw1);                                   \
            pf[2] = __builtin_bit_cast(bf16x8, pw2);                                   \
            pf[3] = __builtin_bit_cast(bf16x8, pw3);                                   \
        }                                                                              \
        NXT0 = f32x16{};                                                               \
        NXT1 = f32x16{};                                                               \
        if (haveV) {                                                                   \
            const char* Kb = (const char*)Kls + ((t_ + 1) & 3) * 8192;                 \
            __builtin_amdgcn_s_setprio(1);                                             \
            _Pragma("unroll")                                                          \
            for (int kc = 0; kc < 4; kc++) {                                           \
                bf16x8 kf0 = *(const bf16x8*)(Kb + koff[kc]);                          \
                bf16x8 kf1 = *(const bf16x8*)(Kb + koff[kc] + 4096);                   \
                NXT0 = MFMA32(kf0, qf[kc], NXT0);                                      \
                NXT1 = MFMA32(kf1, qf[kc], NXT1);                                      \
            }                                                                          \
            __builtin_amdgcn_s_setprio(0);                                             \
        }                                                                              \
        {                                                                              \
            const char* Vb = (const char*)Vt + (t_ & 1) * 8192;                        \
            __builtin_amdgcn_s_setprio(1);                                             \
            _Pragma("unroll")                                                          \
            for (int kc = 0; kc < 4; kc++) {                                           \
                bf16x8 vf0 = *(const bf16x8*)(Vb + vroff[kc]);                         \
                bf16x8 vf1 = *(const bf16x8*)(Vb + vroff[kc] + 4096);                  \
                oacc0 = MFMA32(vf0, pf[kc], oacc0);                                    \
                oacc1 = MFMA32(vf1, pf[kc], oacc1);                                    \
            }                                                                          \
            __builtin_amdgcn_s_setprio(0);                                             \
        }                                                                              \
        asm volatile("s_waitcnt vmcnt(1)" ::: "memory");                               \
        __builtin_amdgcn_sched_barrier(0);                                             \
        if (haveV) {                                                                   \
            _Pragma("unroll")                                                          \
            for (int jj = 0; jj < 4; jj++)                                             \
                *(u32*)((char*)Vt + ((t_ + 1) & 1) * 8192 + vwoff[jj]) =               \
                    __builtin_amdgcn_perm(a1[jj >> 1], a0[jj >> 1],                    \
                                          (jj & 1) ? 0x07060302u : 0x05040100u);       \
        }                                                                              \
        asm volatile("s_waitcnt lgkmcnt(0)" ::: "memory");                             \
        __builtin_amdgcn_sched_barrier(0);                                             \
        __builtin_amdgcn_s_barrier();                                                  \
        if (haveK) kgp += TSTEP;                                                       \
        if (haveV) vgp += TSTEP;                                                       \
    }

    for (int tp = 0; tp < NT / 2; tp++) {
        ATTN_TILE(2 * tp,     sc0, sc1, sn0, sn1)
        ATTN_TILE(2 * tp + 1, sn0, sn1, sc0, sc1)
    }
#undef ATTN_TILE

    const float l_run = (l4[0] + l4[1]) + (l4[2] + l4[3]);
    const float l_tot = l_run + __shfl_xor(l_run, 32);
    u16* op = PO + ((size_t)half * M_TOT + qrow) * E_DIM + h * DH;
    #pragma unroll
    for (int db = 0; db < 2; db++) {
        #pragma unroll
        for (int j = 0; j < 4; j++) {
            u32x2 pk;
            pk[0] = cvt_pk_bf16(db ? oacc1[4 * j + 0] : oacc0[4 * j + 0],
                                db ? oacc1[4 * j + 1] : oacc0[4 * j + 1]);
            pk[1] = cvt_pk_bf16(db ? oacc1[4 * j + 2] : oacc0[4 * j + 2],
                                db ? oacc1[4 * j + 3] : oacc0[4 * j + 3]);
            const int d0 = 32 * db + 8 * j + 4 * hi;
            *reinterpret_cast<u32x2*>(op + d0) = pk;
        }
    }
    if (hi == 0) lws[((size_t)half * M_TOT + qrow) * HNUM + h] = l_tot;
}

// ---------------- combine partials: ab = (PO0 + PO1) / (l0 + l1) ----------------
__global__ __launch_bounds__(256) void combine_kernel(const u16* __restrict__ PO,
                                                      const float* __restrict__ lws,
                                                      u16* __restrict__ ab) {
    const int i = (blockIdx.x * 256 + threadIdx.x) * 8;
    const int row = i >> 10;
    const int h = (i & 1023) >> 6;
    const float l0 = lws[(size_t)row * HNUM + h];
    const float l1 = lws[((size_t)M_TOT + row) * HNUM + h];
    const float rl = 1.0f / (l0 + l1);
    const bf16x8 a = *reinterpret_cast<const bf16x8*>(PO + i);
    const bf16x8 c = *reinterpret_cast<const bf16x8*>(PO + (size_t)M_TOT * E_DIM + i);
    u16x8 o;
    #pragma unroll
    for (int j = 0; j < 8; j++)
        o[j] = f2bf(((float)a[j] + (float)c[j]) * rl);
    *reinterpret_cast<u16x8*>(ab + i) = o;
}

extern "C" void kernel_launch(void* const* d_in, const int* in_sizes, int n_in,
                              void* d_out, int out_size, void* d_ws, size_t ws_size,
                              hipStream_t stream) {
    const float* x  = (const float*)d_in[0];
    const int* mask = (const int*)d_in[1];
    const float* Wq = (const float*)d_in[2];
    const float* bq = (const float*)d_in[3];
    const float* Wk = (const float*)d_in[4];
    const float* bk = (const float*)d_in[5];
    const float* Wv = (const float*)d_in[6];
    const float* bv = (const float*)d_in[7];
    const float* Wo = (const float*)d_in[8];
    const float* bo = (const float*)d_in[9];
    float* out = (float*)d_out;

    u16* ws  = (u16*)d_ws;
    const size_t ME = (size_t)M_TOT * E_DIM;         // 4194304
    u16* xb  = ws;                                   // [M][E] bf16 x ; later reused as ab
    u16* wt  = ws + ME;                              // 4x [E][E] bf16 W^T (q,k,v,o)
    u16* qb  = ws + 2 * ME;                          // Q,K,V contiguous [3][M][E]
    u16* kbf = ws + 3 * ME;
    u16* vbf = ws + 4 * ME;
    u64* mbf = (u64*)(ws + 5 * ME);                  // 64 u64 mask bitmaps (512B)
    float* lws = (float*)(ws + 5 * ME + 8192);       // [2][M][H] f32 l-partials (512KB)
    u16* ab  = xb;                                   // attn concat aliases xb
    u16* po  = (u16*)d_out;                          // partial O scratch: 2x[M][E] bf16 = 16MB

    prep_kernel<<<dim3(M_TOT * E_DIM / 1024 + 4096), dim3(256), 0, stream>>>(
        x, xb, mask, mbf, Wq, Wk, Wv, Wo, wt);
    gemm_kernel<u16><<<dim3(E_DIM / 128, M_TOT / 128, 3), dim3(256), 0, stream>>>(
        xb, wt, qb, bq, bk, bv, 0.125f * LOG2E, M_TOT);
    attn_kernel<<<dim3(512), dim3(512), 0, stream>>>(qb, kbf, vbf, mbf, po, lws);
    combine_kernel<<<dim3(M_TOT * E_DIM / 2048), dim3(256), 0, stream>>>(po, lws, ab);
    gemm_kernel<float><<<dim3(E_DIM / 128, M_TOT / 128, 1), dim3(256), 0, stream>>>(
        ab, wt + (size_t)3 * E_DIM * E_DIM, out, bo, bo, bo, 1.0f, M_TOT);
}